// Round 14
// baseline (241.598 us; speedup 1.0000x reference)
//
#include <hip/hip_runtime.h>
#include <math.h>

#define DMODEL 384
#define DIN 768
#define NST 16
#define DTR 48
#define BSZ 8
#define LSEQ 1024
#define NROWS (BSZ*LSEQ)      // 8192
#define XPO_W (DTR + 2*NST)   // 80
#define CL 32                 // chunk length for scan
#define NC (LSEQ/CL)          // 32 chunks
#define CSEG 32               // conv segment length

typedef __attribute__((ext_vector_type(8))) short bf16x8;
typedef __attribute__((ext_vector_type(4))) float f32x4;

__device__ __forceinline__ unsigned short f2bf(float x) {
  unsigned int u = __float_as_uint(x);
  unsigned int r = u + 0x7fffu + ((u >> 16) & 1u);
  return (unsigned short)(r >> 16);
}
__device__ __forceinline__ float bf2f(unsigned short h) {
  return __uint_as_float(((unsigned int)h) << 16);
}
__device__ __forceinline__ unsigned int pk2(float a, float b) {
  return (unsigned int)f2bf(a) | ((unsigned int)f2bf(b) << 16);
}

__device__ __forceinline__ void gll16(const void* g, void* l) {
  __builtin_amdgcn_global_load_lds(
      (const __attribute__((address_space(1))) void*)g,
      (__attribute__((address_space(3))) void*)l, 16, 0, 0);
}

// ---------------- fused prep: weight splits + LayerNorm ----------------
__device__ __forceinline__ void split_one(const float* src, int ldsrc, int R, int C,
    unsigned short* dh, unsigned short* dl, int Cpad, int i) {
  int r = i / Cpad, c = i - r * Cpad;
  float v = (r < R && c < C) ? src[(size_t)r*ldsrc + c] : 0.f;
  unsigned short hv = f2bf(v);
  dh[i] = hv;
  dl[i] = f2bf(v - bf2f(hv));
}
#define N_INW (1536*384)
#define N_XW  (128*768)
#define N_DTW (768*64)
#define N_OW  (384*768)
#define NWBLK ((N_INW+N_XW+N_DTW+N_OW)/256)   // 4032
__global__ __launch_bounds__(256) void prep_kernel(
    const float* __restrict__ inw, const float* __restrict__ xw,
    const float* __restrict__ dtw, const float* __restrict__ ow,
    unsigned short* inw_h, unsigned short* inw_l,
    unsigned short* xw_h, unsigned short* xw_l,
    unsigned short* dtw_h, unsigned short* dtw_l,
    unsigned short* ow_h, unsigned short* ow_l,
    const float* __restrict__ x, const float* __restrict__ g,
    const float* __restrict__ b,
    unsigned short* __restrict__ xh, unsigned short* __restrict__ xl) {
  if (blockIdx.x < NWBLK) {
    int i = blockIdx.x * 256 + threadIdx.x;
    if (i < N_INW) { split_one(inw, 384, 1536, 384, inw_h, inw_l, 384, i); return; }
    i -= N_INW;
    if (i < N_XW)  { split_one(xw, 768, 80, 768, xw_h, xw_l, 768, i); return; }
    i -= N_XW;
    if (i < N_DTW) { split_one(dtw, 48, 768, 48, dtw_h, dtw_l, 64, i); return; }
    i -= N_DTW;
    split_one(ow, 768, 384, 768, ow_h, ow_l, 768, i);
    return;
  }
  // LayerNorm path: 4 rows per block
  int row = (blockIdx.x - NWBLK) * 4 + (threadIdx.x >> 6);
  int lane = threadIdx.x & 63;
  const float* xr = x + (size_t)row * DMODEL;
  float v[6];
  float s = 0.f, ss = 0.f;
#pragma unroll
  for (int i = 0; i < 6; ++i) { v[i] = xr[lane + i*64]; s += v[i]; ss += v[i]*v[i]; }
#pragma unroll
  for (int off = 32; off; off >>= 1) { s += __shfl_xor(s, off); ss += __shfl_xor(ss, off); }
  float mu = s * (1.f / DMODEL);
  float var = ss * (1.f / DMODEL) - mu * mu;
  float inv = rsqrtf(var + 1e-5f);
#pragma unroll
  for (int i = 0; i < 6; ++i) {
    int c = lane + i*64;
    float o = (v[i] - mu) * inv * g[c] + b[c];
    unsigned short hv = f2bf(o);
    xh[(size_t)row*DMODEL + c] = hv;
    xl[(size_t)row*DMODEL + c] = f2bf(o - bf2f(hv));
  }
}

// ---------------- MFMA split-bf16 GEMM, 2-phase double-buffered (R3-proven) -------------
// C[M,N] (z-slice) = (Ah+Al)[M,K] * (Bh+Bl)[N,K]^T, 3 MFMA terms.
// EPI: 0 plain, 2 bias+softplus, 5 in_proj (x-half fp32 to C, z-half silu->bf16 to sz)
template<int EPI>
__global__ __launch_bounds__(256, 2) void gemm_mfma(
    const unsigned short* __restrict__ Ah, const unsigned short* __restrict__ Al, int lda,
    const unsigned short* __restrict__ Bh, const unsigned short* __restrict__ Bl, int ldb,
    float* __restrict__ C, int ldc, size_t strideS,
    const float* __restrict__ bias, unsigned short* __restrict__ sz,
    int T) {
  // [buf][arr: Ah,Al,Bh,Bl][cell(512) x 8 bf16] = 64 KB
  __shared__ unsigned short lds[2][4][4096];
  int tid = threadIdx.x;
  int lane = tid & 63, wid = tid >> 6;
  int wm = wid >> 1, wn = wid & 1;

  // bijective XCD swizzle over (x,y); all grids have nwg % 8 == 0
  unsigned nwg = gridDim.x * gridDim.y;
  unsigned bid = blockIdx.y * gridDim.x + blockIdx.x;
  unsigned cpx = nwg >> 3;
  unsigned sw = (bid & 7) * cpx + (bid >> 3);
  unsigned bx = sw % gridDim.x, by = sw / gridDim.x;
  int m0 = by * 128, n0 = bx * 128;
  C += (size_t)blockIdx.z * strideS;
  size_t kofs = (size_t)blockIdx.z * T * 32;

  f32x4 acc[4][4];
#pragma unroll
  for (int i = 0; i < 4; ++i)
#pragma unroll
    for (int j = 0; j < 4; ++j) acc[i][j] = (f32x4){0.f, 0.f, 0.f, 0.f};

  int kgl = lane >> 4, rl = lane & 15;

  // per-wave staging geometry: wave fills cells [wid*128, wid*128+128) per array
  int c0 = wid*128 + lane;        // j=0 cell
  int c1 = wid*128 + 64 + lane;   // j=1 cell
  int r0 = c0 & 127, kg0 = c0 >> 7;
  int r1 = c1 & 127, kg1 = c1 >> 7;

#define STAGE(bf, kt) do { \
    size_t ga0 = (size_t)(m0 + r0) * lda + (kt) + kg0*8 + kofs; \
    size_t gb0 = (size_t)(n0 + r0) * ldb + (kt) + kg0*8 + kofs; \
    size_t ga1 = (size_t)(m0 + r1) * lda + (kt) + kg1*8 + kofs; \
    size_t gb1 = (size_t)(n0 + r1) * ldb + (kt) + kg1*8 + kofs; \
    gll16(Ah + ga0, &lds[bf][0][(wid*128)*8]); \
    gll16(Al + ga0, &lds[bf][1][(wid*128)*8]); \
    gll16(Bh + gb0, &lds[bf][2][(wid*128)*8]); \
    gll16(Bl + gb0, &lds[bf][3][(wid*128)*8]); \
    gll16(Ah + ga1, &lds[bf][0][(wid*128+64)*8]); \
    gll16(Al + ga1, &lds[bf][1][(wid*128+64)*8]); \
    gll16(Bh + gb1, &lds[bf][2][(wid*128+64)*8]); \
    gll16(Bl + gb1, &lds[bf][3][(wid*128+64)*8]); \
  } while (0)

  STAGE(0, 0);
  asm volatile("s_waitcnt vmcnt(0)" ::: "memory");
  __builtin_amdgcn_s_barrier();

  int cur = 0;
  for (int t = 0; t < T; ++t) {
    if (t + 1 < T) {
      STAGE(cur ^ 1, (t + 1) << 5);
    }
    asm volatile("" ::: "memory");
    bf16x8 ah[4], al[4], bh[4], bl[4];
#pragma unroll
    for (int mi = 0; mi < 4; ++mi) {
      int cell = kgl*128 + wm*64 + mi*16 + rl;
      ah[mi] = *reinterpret_cast<const bf16x8*>(&lds[cur][0][cell*8]);
      al[mi] = *reinterpret_cast<const bf16x8*>(&lds[cur][1][cell*8]);
    }
#pragma unroll
    for (int ni = 0; ni < 4; ++ni) {
      int cell = kgl*128 + wn*64 + ni*16 + rl;
      bh[ni] = *reinterpret_cast<const bf16x8*>(&lds[cur][2][cell*8]);
      bl[ni] = *reinterpret_cast<const bf16x8*>(&lds[cur][3][cell*8]);
    }
#pragma unroll
    for (int mi = 0; mi < 4; ++mi)
#pragma unroll
      for (int ni = 0; ni < 4; ++ni) {
        acc[mi][ni] = __builtin_amdgcn_mfma_f32_16x16x32_bf16(ah[mi], bh[ni], acc[mi][ni], 0, 0, 0);
        acc[mi][ni] = __builtin_amdgcn_mfma_f32_16x16x32_bf16(al[mi], bh[ni], acc[mi][ni], 0, 0, 0);
        acc[mi][ni] = __builtin_amdgcn_mfma_f32_16x16x32_bf16(ah[mi], bl[ni], acc[mi][ni], 0, 0, 0);
      }
    asm volatile("s_waitcnt vmcnt(0)" ::: "memory");
    __builtin_amdgcn_s_barrier();
    cur ^= 1;
  }
#undef STAGE

  // epilogue: C/D frag layout col=lane&15, row=(lane>>4)*4+j
#pragma unroll
  for (int mi = 0; mi < 4; ++mi)
#pragma unroll
    for (int ni = 0; ni < 4; ++ni)
#pragma unroll
      for (int j = 0; j < 4; ++j) {
        int m = m0 + wm*64 + mi*16 + (lane>>4)*4 + j;
        int n = n0 + wn*64 + ni*16 + (lane&15);
        float v = acc[mi][ni][j];
        if (EPI == 0) {
          C[(size_t)m*ldc + n] = v;
        } else if (EPI == 2) {
          v += bias[n];
          v = (v > 20.f) ? v : log1pf(__expf(v));
          C[(size_t)m*ldc + n] = v;
        } else if (EPI == 5) {
          if (n < DIN) {
            C[(size_t)m*DIN + n] = v;                       // x-half fp32 for conv
          } else {
            float s = v / (1.f + __expf(-v));               // silu(z) -> bf16
            sz[(size_t)m*DIN + (n - DIN)] = f2bf(s);
          }
        }
      }
}

// ---------------- x_proj split-K(6) reduce: -> xpo fp32 + dlow hi/lo ----------
__global__ __launch_bounds__(256) void reduce_xproj(
    const float* __restrict__ P, float* __restrict__ xpo,
    unsigned short* __restrict__ dh, unsigned short* __restrict__ dl) {
  int idx = blockIdx.x * 256 + threadIdx.x;   // NROWS*128
  int m = idx >> 7, n = idx & 127;
  float v = 0.f;
#pragma unroll
  for (int s = 0; s < 6; ++s) v += P[(size_t)s * NROWS * 128 + idx];
  if (n < XPO_W) xpo[(size_t)m * XPO_W + n] = v;
  if (n < 64) {   // cols 48..63 multiply dtw zeros -> harmless
    unsigned short hv = f2bf(v);
    dh[(size_t)m*64 + n] = hv;
    dl[(size_t)m*64 + n] = f2bf(v - bf2f(hv));
  }
}

// ---------------- out_proj split-K(4) reduce + residual -> d_out ----------------
__global__ __launch_bounds__(256) void reduce_out(
    const float* __restrict__ P, const float* __restrict__ x, float* __restrict__ out) {
  int i = blockIdx.x * 256 + threadIdx.x;     // NROWS*DMODEL
  const size_t S = (size_t)NROWS*DMODEL;
  out[i] = x[i] + ((P[i] + P[i + S]) + (P[i + 2*S] + P[i + 3*S]));
}

// ---------------- causal depthwise conv + SiLU: read-once register-rolling ----------------
__global__ __launch_bounds__(256) void conv_silu_kernel(
    const float* __restrict__ xh32, const float* __restrict__ w,
    const float* __restrict__ cb,
    unsigned short* __restrict__ uh, unsigned short* __restrict__ ul) {
  int d = blockIdx.x * 256 + threadIdx.x;     // channel
  int l0 = blockIdx.y * CSEG;                 // segment start
  int b = blockIdx.z;
  float xv[CSEG + 3];
#pragma unroll
  for (int i = 0; i < CSEG + 3; ++i) {
    int l = l0 + i - 3;
    xv[i] = (l >= 0) ? xh32[((size_t)b*LSEQ + l) * DIN + d] : 0.f;
  }
  float w0 = w[d*4], w1 = w[d*4+1], w2 = w[d*4+2], w3 = w[d*4+3];
  float cbv = cb[d];
#pragma unroll
  for (int i = 0; i < CSEG; ++i) {
    float acc = cbv;
    acc = fmaf(xv[i],     w0, acc);
    acc = fmaf(xv[i + 1], w1, acc);
    acc = fmaf(xv[i + 2], w2, acc);
    acc = fmaf(xv[i + 3], w3, acc);
    float s = acc / (1.f + __expf(-acc));     // silu
    size_t idx = ((size_t)b*LSEQ + l0 + i) * DIN + d;
    unsigned short hv = f2bf(s);
    uh[idx] = hv;
    ul[idx] = f2bf(s - bf2f(hv));
  }
}

// ---------------- chunked selective scan (NC=32, CL=32, bf16 carries, u hi-only) ----------
__global__ __launch_bounds__(256) void scan_pass1(
    const float* __restrict__ delta,
    const unsigned short* __restrict__ uh,
    const float* __restrict__ xpo, const float* __restrict__ A_log,
    unsigned short* __restrict__ carryA, unsigned short* __restrict__ carryH) {
  int d = blockIdx.x * 256 + threadIdx.x;
  int c = blockIdx.y, b = blockIdx.z;
  float A[16];
  {
    const float4* al = reinterpret_cast<const float4*>(A_log + (size_t)d * NST);
#pragma unroll
    for (int i = 0; i < 4; ++i) {
      float4 t = al[i];
      A[4*i+0] = -__expf(t.x); A[4*i+1] = -__expf(t.y);
      A[4*i+2] = -__expf(t.z); A[4*i+3] = -__expf(t.w);
    }
  }
  float h[16], ap[16];
#pragma unroll
  for (int n = 0; n < 16; ++n) { h[n] = 0.f; ap[n] = 1.f; }
  const float* dp = delta + ((size_t)b*LSEQ + c*CL) * DIN + d;
  const unsigned short* uhp = uh + ((size_t)b*LSEQ + c*CL) * DIN + d;
  const float* bp = xpo   + ((size_t)b*LSEQ + c*CL) * XPO_W + DTR;
  for (int l = 0; l < CL; ++l) {
    float dv = dp[(size_t)l*DIN];
    float uv = bf2f(uhp[(size_t)l*DIN]);
    float du = dv * uv;
    float Bv[16];
    {
      const float4* b4 = reinterpret_cast<const float4*>(bp + (size_t)l*XPO_W);
#pragma unroll
      for (int i = 0; i < 4; ++i) {
        float4 t = b4[i];
        Bv[4*i+0] = t.x; Bv[4*i+1] = t.y; Bv[4*i+2] = t.z; Bv[4*i+3] = t.w;
      }
    }
#pragma unroll
    for (int n = 0; n < 16; ++n) {
      float a = __expf(dv * A[n]);
      ap[n] *= a;
      h[n] = fmaf(a, h[n], du * Bv[n]);
    }
  }
  size_t ci = (((size_t)b*NC + c) * DIN + d) * NST;   // bf16 elements
  uint4* ca = reinterpret_cast<uint4*>(carryA + ci);
  uint4* ch = reinterpret_cast<uint4*>(carryH + ci);
  ca[0] = make_uint4(pk2(ap[0],ap[1]), pk2(ap[2],ap[3]), pk2(ap[4],ap[5]), pk2(ap[6],ap[7]));
  ca[1] = make_uint4(pk2(ap[8],ap[9]), pk2(ap[10],ap[11]), pk2(ap[12],ap[13]), pk2(ap[14],ap[15]));
  ch[0] = make_uint4(pk2(h[0],h[1]), pk2(h[2],h[3]), pk2(h[4],h[5]), pk2(h[6],h[7]));
  ch[1] = make_uint4(pk2(h[8],h[9]), pk2(h[10],h[11]), pk2(h[12],h[13]), pk2(h[14],h[15]));
}

__global__ __launch_bounds__(256) void scan_mid(
    const unsigned short* __restrict__ carryA, unsigned short* __restrict__ carryH) {
  int idx = blockIdx.x * 256 + threadIdx.x;   // [0, BSZ*DIN*NST)
  int b = idx / (DIN*NST);
  int rem = idx - b * DIN*NST;
  float h = 0.f;
#pragma unroll
  for (int c = 0; c < NC; ++c) {
    size_t i = ((size_t)b*NC + c) * (DIN*NST) + rem;
    float a = bf2f(carryA[i]);
    float e = bf2f(carryH[i]);
    carryH[i] = f2bf(h);
    h = fmaf(a, h, e);
  }
}

__global__ __launch_bounds__(256) void scan_pass2(
    const float* __restrict__ delta,
    const unsigned short* __restrict__ uh,
    const float* __restrict__ xpo, const unsigned short* __restrict__ sz,
    const float* __restrict__ A_log, const float* __restrict__ Dp,
    const unsigned short* __restrict__ carryH,
    unsigned short* __restrict__ yh, unsigned short* __restrict__ yl) {
  int d = blockIdx.x * 256 + threadIdx.x;
  int c = blockIdx.y, b = blockIdx.z;
  float A[16];
  {
    const float4* al = reinterpret_cast<const float4*>(A_log + (size_t)d * NST);
#pragma unroll
    for (int i = 0; i < 4; ++i) {
      float4 t = al[i];
      A[4*i+0] = -__expf(t.x); A[4*i+1] = -__expf(t.y);
      A[4*i+2] = -__expf(t.z); A[4*i+3] = -__expf(t.w);
    }
  }
  float h[16];
  size_t ci = (((size_t)b*NC + c) * DIN + d) * NST;
  {
    const uint4* ch4 = reinterpret_cast<const uint4*>(carryH + ci);
    uint4 t0 = ch4[0], t1 = ch4[1];
    h[0] = bf2f(t0.x & 0xffff); h[1] = bf2f(t0.x >> 16);
    h[2] = bf2f(t0.y & 0xffff); h[3] = bf2f(t0.y >> 16);
    h[4] = bf2f(t0.z & 0xffff); h[5] = bf2f(t0.z >> 16);
    h[6] = bf2f(t0.w & 0xffff); h[7] = bf2f(t0.w >> 16);
    h[8] = bf2f(t1.x & 0xffff); h[9] = bf2f(t1.x >> 16);
    h[10] = bf2f(t1.y & 0xffff); h[11] = bf2f(t1.y >> 16);
    h[12] = bf2f(t1.z & 0xffff); h[13] = bf2f(t1.z >> 16);
    h[14] = bf2f(t1.w & 0xffff); h[15] = bf2f(t1.w >> 16);
  }
  float Dd = Dp[d];
  const float* dp = delta + ((size_t)b*LSEQ + c*CL) * DIN + d;
  const unsigned short* uhp = uh + ((size_t)b*LSEQ + c*CL) * DIN + d;
  const float* bp = xpo   + ((size_t)b*LSEQ + c*CL) * XPO_W + DTR;
  const unsigned short* szp = sz + ((size_t)b*LSEQ + c*CL) * DIN + d;
  size_t yi0 = ((size_t)b*LSEQ + c*CL) * DIN + d;
  for (int l = 0; l < CL; ++l) {
    float dv = dp[(size_t)l*DIN];
    float uv = bf2f(uhp[(size_t)l*DIN]);
    float du = dv * uv;
    float Bv[16], Cv[16];
    {
      const float4* b4 = reinterpret_cast<const float4*>(bp + (size_t)l*XPO_W);
#pragma unroll
      for (int i = 0; i < 4; ++i) {
        float4 t = b4[i];
        Bv[4*i+0] = t.x; Bv[4*i+1] = t.y; Bv[4*i+2] = t.z; Bv[4*i+3] = t.w;
        float4 tc = b4[i+4];
        Cv[4*i+0] = tc.x; Cv[4*i+1] = tc.y; Cv[4*i+2] = tc.z; Cv[4*i+3] = tc.w;
      }
    }
    float p = 0.f;
#pragma unroll
    for (int n = 0; n < 16; ++n) {
      float a = __expf(dv * A[n]);
      h[n] = fmaf(a, h[n], du * Bv[n]);
      p = fmaf(h[n], Cv[n], p);
    }
    float sv = bf2f(szp[(size_t)l*DIN]);
    float yv = fmaf(uv, Dd, p) * sv;
    unsigned short hv = f2bf(yv);
    yh[yi0 + (size_t)l*DIN] = hv;
    yl[yi0 + (size_t)l*DIN] = f2bf(yv - bf2f(hv));
  }
}

extern "C" void kernel_launch(void* const* d_in, const int* in_sizes, int n_in,
                              void* d_out, int out_size, void* d_ws, size_t ws_size,
                              hipStream_t stream) {
  const float* x          = (const float*)d_in[0];
  const float* ln_g       = (const float*)d_in[1];
  const float* ln_b       = (const float*)d_in[2];
  const float* in_proj_w  = (const float*)d_in[3];   // (1536,384)
  const float* conv_w     = (const float*)d_in[4];   // (768,1,4)
  const float* conv_b     = (const float*)d_in[5];
  const float* x_proj_w   = (const float*)d_in[6];   // (80,768)
  const float* dt_proj_w  = (const float*)d_in[7];   // (768,48)
  const float* dt_proj_b  = (const float*)d_in[8];
  const float* A_log      = (const float*)d_in[9];   // (768,16)
  const float* D_param    = (const float*)d_in[10];
  const float* out_proj_w = (const float*)d_in[11];  // (384,768)

  char* w = (char*)d_ws;
  // region1 (12.58MB): xn hi/lo -> dlow hi/lo -> bf16 carryA/H (lifetimes disjoint)
  unsigned short* xn_h  = (unsigned short*)w;
  unsigned short* xn_l  = xn_h + (size_t)NROWS*DMODEL;
  unsigned short* dlow_h = (unsigned short*)w;
  unsigned short* dlow_l = dlow_h + (size_t)NROWS*64;
  unsigned short* carryA = (unsigned short*)w;                       // 6.29MB
  unsigned short* carryH = carryA + (size_t)BSZ*NC*DIN*NST;          // 6.29MB
  char* p = w + (size_t)NROWS*DMODEL*4;               // 12.58MB
  // region2 (50.33MB): xh32 fp32 (25.17) + sz bf16 (12.58) -> later out_proj partials (4x12.58)
  float* xh32 = (float*)p;
  unsigned short* sz = (unsigned short*)(p + (size_t)NROWS*DIN*4);
  float* opart = (float*)p;           p += (size_t)NROWS*2*DIN*4;
  unsigned short* u_h = (unsigned short*)p;
  unsigned short* u_l = u_h + (size_t)NROWS*DIN;      p += (size_t)NROWS*DIN*4; // 25.17MB
  float* xpo = (float*)p;             p += (size_t)NROWS*XPO_W*4;   // 2.62MB
  float* delta = (float*)p;           p += (size_t)NROWS*DIN*4;     // 25.17MB
  // weight splits for in_proj/x_proj live in the (not yet written) delta region
  unsigned short* inw_h = (unsigned short*)delta;
  unsigned short* inw_l = inw_h + (size_t)1536*384;
  unsigned short* xw_h  = inw_l + (size_t)1536*384;
  unsigned short* xw_l  = xw_h + (size_t)128*768;
  // xpart region (25.17MB): x_proj S=6 partials (exactly fills) -> later y2 hi/lo
  unsigned short* y2_h = (unsigned short*)p;
  unsigned short* y2_l = y2_h + (size_t)NROWS*DIN;
  float* xpart = (float*)p;           p += (size_t)NROWS*DIN*4;
  unsigned short* dtw_h = (unsigned short*)p;
  unsigned short* dtw_l = dtw_h + (size_t)768*64;
  unsigned short* ow_h  = dtw_l + (size_t)768*64;
  unsigned short* ow_l  = ow_h + (size_t)384*768;

  // 0. fused prep: weight splits + LayerNorm
  prep_kernel<<<NWBLK + NROWS/4, 256, 0, stream>>>(
      in_proj_w, x_proj_w, dt_proj_w, out_proj_w,
      inw_h, inw_l, xw_h, xw_l, dtw_h, dtw_l, ow_h, ow_l,
      x, ln_g, ln_b, xn_h, xn_l);

  // 1. in_proj (EPI=5): x-half fp32 -> xh32, z-half silu -> sz bf16   (T=12)
  gemm_mfma<5><<<dim3(12, 64, 1), 256, 0, stream>>>(xn_h, xn_l, DMODEL, inw_h, inw_l, DMODEL,
      xh32, DIN, 0, nullptr, sz, 12);

  // 2. conv + silu -> u hi/lo (read-once, register-rolling)
  conv_silu_kernel<<<dim3(DIN/256, LSEQ/CSEG, BSZ), 256, 0, stream>>>(
      xh32, conv_w, conv_b, u_h, u_l);

  // 3. x_proj: split-K partials (S=6, T=4 each) then reduce -> xpo fp32 + dlow hi/lo
  gemm_mfma<0><<<dim3(1, 64, 6), 256, 0, stream>>>(u_h, u_l, DIN, xw_h, xw_l, DIN,
      xpart, 128, (size_t)NROWS*128, nullptr, nullptr, 4);
  reduce_xproj<<<(NROWS*128)/256, 256, 0, stream>>>(xpart, xpo, dlow_h, dlow_l);

  // 4. dt_proj + bias + softplus -> delta   (M=8192, N=768, Kpad=64, T=2)
  gemm_mfma<2><<<dim3(6, 64, 1), 256, 0, stream>>>(dlow_h, dlow_l, 64, dtw_h, dtw_l, 64,
      delta, DIN, 0, dt_proj_b, nullptr, 2);

  // 5. chunked selective scan (NC=32) -> y2 hi/lo (overwrites dead xpart)
  {
    dim3 g1(DIN/256, NC, BSZ);
    scan_pass1<<<g1, 256, 0, stream>>>(delta, u_h, xpo, A_log, carryA, carryH);
    scan_mid<<<(BSZ*DIN*NST)/256, 256, 0, stream>>>(carryA, carryH);
    scan_pass2<<<g1, 256, 0, stream>>>(delta, u_h, xpo, sz, A_log, D_param,
                                       carryH, y2_h, y2_l);
  }

  // 6. out_proj split-K (S=4, T=6) -> partials overwrite region2, then reduce + residual
  gemm_mfma<0><<<dim3(3, 64, 4), 256, 0, stream>>>(y2_h, y2_l, DIN, ow_h, ow_l, DIN,
      opart, DMODEL, (size_t)NROWS*DMODEL, nullptr, nullptr, 6);
  reduce_out<<<(NROWS*DMODEL)/256, 256, 0, stream>>>(opart, x, (float*)d_out);
}

// Round 15
// 225.929 us; speedup vs baseline: 1.0694x; 1.0694x over previous
//
#include <hip/hip_runtime.h>
#include <math.h>

#define DMODEL 384
#define DIN 768
#define NST 16
#define DTR 48
#define BSZ 8
#define LSEQ 1024
#define NROWS (BSZ*LSEQ)      // 8192
#define XPO_W (DTR + 2*NST)   // 80
#define CL 32                 // chunk length for scan
#define NC (LSEQ/CL)          // 32 chunks
#define CSEG 32               // conv segment length

typedef __attribute__((ext_vector_type(8))) short bf16x8;
typedef __attribute__((ext_vector_type(4))) float f32x4;

__device__ __forceinline__ unsigned short f2bf(float x) {
  unsigned int u = __float_as_uint(x);
  unsigned int r = u + 0x7fffu + ((u >> 16) & 1u);
  return (unsigned short)(r >> 16);
}
__device__ __forceinline__ float bf2f(unsigned short h) {
  return __uint_as_float(((unsigned int)h) << 16);
}
__device__ __forceinline__ unsigned int pk2(float a, float b) {
  return (unsigned int)f2bf(a) | ((unsigned int)f2bf(b) << 16);
}

__device__ __forceinline__ void gll16(const void* g, void* l) {
  __builtin_amdgcn_global_load_lds(
      (const __attribute__((address_space(1))) void*)g,
      (__attribute__((address_space(3))) void*)l, 16, 0, 0);
}

// ---------------- fused prep: weight splits + LayerNorm ----------------
__device__ __forceinline__ void split_one(const float* src, int ldsrc, int R, int C,
    unsigned short* dh, unsigned short* dl, int Cpad, int i) {
  int r = i / Cpad, c = i - r * Cpad;
  float v = (r < R && c < C) ? src[(size_t)r*ldsrc + c] : 0.f;
  unsigned short hv = f2bf(v);
  dh[i] = hv;
  dl[i] = f2bf(v - bf2f(hv));
}
#define N_INW (1536*384)
#define N_XW  (128*768)
#define N_DTW (768*64)
#define N_OW  (384*768)
#define NWBLK ((N_INW+N_XW+N_DTW+N_OW)/256)   // 4032
__global__ __launch_bounds__(256) void prep_kernel(
    const float* __restrict__ inw, const float* __restrict__ xw,
    const float* __restrict__ dtw, const float* __restrict__ ow,
    unsigned short* inw_h, unsigned short* inw_l,
    unsigned short* xw_h, unsigned short* xw_l,
    unsigned short* dtw_h, unsigned short* dtw_l,
    unsigned short* ow_h, unsigned short* ow_l,
    const float* __restrict__ x, const float* __restrict__ g,
    const float* __restrict__ b,
    unsigned short* __restrict__ xh, unsigned short* __restrict__ xl) {
  if (blockIdx.x < NWBLK) {
    int i = blockIdx.x * 256 + threadIdx.x;
    if (i < N_INW) { split_one(inw, 384, 1536, 384, inw_h, inw_l, 384, i); return; }
    i -= N_INW;
    if (i < N_XW)  { split_one(xw, 768, 80, 768, xw_h, xw_l, 768, i); return; }
    i -= N_XW;
    if (i < N_DTW) { split_one(dtw, 48, 768, 48, dtw_h, dtw_l, 64, i); return; }
    i -= N_DTW;
    split_one(ow, 768, 384, 768, ow_h, ow_l, 768, i);
    return;
  }
  // LayerNorm path: 4 rows per block
  int row = (blockIdx.x - NWBLK) * 4 + (threadIdx.x >> 6);
  int lane = threadIdx.x & 63;
  const float* xr = x + (size_t)row * DMODEL;
  float v[6];
  float s = 0.f, ss = 0.f;
#pragma unroll
  for (int i = 0; i < 6; ++i) { v[i] = xr[lane + i*64]; s += v[i]; ss += v[i]*v[i]; }
#pragma unroll
  for (int off = 32; off; off >>= 1) { s += __shfl_xor(s, off); ss += __shfl_xor(ss, off); }
  float mu = s * (1.f / DMODEL);
  float var = ss * (1.f / DMODEL) - mu * mu;
  float inv = rsqrtf(var + 1e-5f);
#pragma unroll
  for (int i = 0; i < 6; ++i) {
    int c = lane + i*64;
    float o = (v[i] - mu) * inv * g[c] + b[c];
    unsigned short hv = f2bf(o);
    xh[(size_t)row*DMODEL + c] = hv;
    xl[(size_t)row*DMODEL + c] = f2bf(o - bf2f(hv));
  }
}

// ---------------- MFMA split-bf16 GEMM, 2-phase double-buffered (R3-proven) -------------
// C[M,N] (z-slice) = (Ah+Al)[M,K] * (Bh+Bl)[N,K]^T, 3 MFMA terms.
// EPI: 0 plain, 2 bias+softplus
template<int EPI>
__global__ __launch_bounds__(256, 2) void gemm_mfma(
    const unsigned short* __restrict__ Ah, const unsigned short* __restrict__ Al, int lda,
    const unsigned short* __restrict__ Bh, const unsigned short* __restrict__ Bl, int ldb,
    float* __restrict__ C, int ldc, size_t strideS,
    const float* __restrict__ bias,
    int T) {
  // [buf][arr: Ah,Al,Bh,Bl][cell(512) x 8 bf16] = 64 KB
  __shared__ unsigned short lds[2][4][4096];
  int tid = threadIdx.x;
  int lane = tid & 63, wid = tid >> 6;
  int wm = wid >> 1, wn = wid & 1;

  // bijective XCD swizzle over (x,y); all grids have nwg % 8 == 0
  unsigned nwg = gridDim.x * gridDim.y;
  unsigned bid = blockIdx.y * gridDim.x + blockIdx.x;
  unsigned cpx = nwg >> 3;
  unsigned sw = (bid & 7) * cpx + (bid >> 3);
  unsigned bx = sw % gridDim.x, by = sw / gridDim.x;
  int m0 = by * 128, n0 = bx * 128;
  C += (size_t)blockIdx.z * strideS;
  size_t kofs = (size_t)blockIdx.z * T * 32;

  f32x4 acc[4][4];
#pragma unroll
  for (int i = 0; i < 4; ++i)
#pragma unroll
    for (int j = 0; j < 4; ++j) acc[i][j] = (f32x4){0.f, 0.f, 0.f, 0.f};

  int kgl = lane >> 4, rl = lane & 15;

  // per-wave staging geometry: wave fills cells [wid*128, wid*128+128) per array
  int c0 = wid*128 + lane;        // j=0 cell
  int c1 = wid*128 + 64 + lane;   // j=1 cell
  int r0 = c0 & 127, kg0 = c0 >> 7;
  int r1 = c1 & 127, kg1 = c1 >> 7;

#define STAGE(bf, kt) do { \
    size_t ga0 = (size_t)(m0 + r0) * lda + (kt) + kg0*8 + kofs; \
    size_t gb0 = (size_t)(n0 + r0) * ldb + (kt) + kg0*8 + kofs; \
    size_t ga1 = (size_t)(m0 + r1) * lda + (kt) + kg1*8 + kofs; \
    size_t gb1 = (size_t)(n0 + r1) * ldb + (kt) + kg1*8 + kofs; \
    gll16(Ah + ga0, &lds[bf][0][(wid*128)*8]); \
    gll16(Al + ga0, &lds[bf][1][(wid*128)*8]); \
    gll16(Bh + gb0, &lds[bf][2][(wid*128)*8]); \
    gll16(Bl + gb0, &lds[bf][3][(wid*128)*8]); \
    gll16(Ah + ga1, &lds[bf][0][(wid*128+64)*8]); \
    gll16(Al + ga1, &lds[bf][1][(wid*128+64)*8]); \
    gll16(Bh + gb1, &lds[bf][2][(wid*128+64)*8]); \
    gll16(Bl + gb1, &lds[bf][3][(wid*128+64)*8]); \
  } while (0)

  STAGE(0, 0);
  asm volatile("s_waitcnt vmcnt(0)" ::: "memory");
  __builtin_amdgcn_s_barrier();

  int cur = 0;
  for (int t = 0; t < T; ++t) {
    if (t + 1 < T) {
      STAGE(cur ^ 1, (t + 1) << 5);
    }
    asm volatile("" ::: "memory");
    bf16x8 ah[4], al[4], bh[4], bl[4];
#pragma unroll
    for (int mi = 0; mi < 4; ++mi) {
      int cell = kgl*128 + wm*64 + mi*16 + rl;
      ah[mi] = *reinterpret_cast<const bf16x8*>(&lds[cur][0][cell*8]);
      al[mi] = *reinterpret_cast<const bf16x8*>(&lds[cur][1][cell*8]);
    }
#pragma unroll
    for (int ni = 0; ni < 4; ++ni) {
      int cell = kgl*128 + wn*64 + ni*16 + rl;
      bh[ni] = *reinterpret_cast<const bf16x8*>(&lds[cur][2][cell*8]);
      bl[ni] = *reinterpret_cast<const bf16x8*>(&lds[cur][3][cell*8]);
    }
#pragma unroll
    for (int mi = 0; mi < 4; ++mi)
#pragma unroll
      for (int ni = 0; ni < 4; ++ni) {
        acc[mi][ni] = __builtin_amdgcn_mfma_f32_16x16x32_bf16(ah[mi], bh[ni], acc[mi][ni], 0, 0, 0);
        acc[mi][ni] = __builtin_amdgcn_mfma_f32_16x16x32_bf16(al[mi], bh[ni], acc[mi][ni], 0, 0, 0);
        acc[mi][ni] = __builtin_amdgcn_mfma_f32_16x16x32_bf16(ah[mi], bl[ni], acc[mi][ni], 0, 0, 0);
      }
    asm volatile("s_waitcnt vmcnt(0)" ::: "memory");
    __builtin_amdgcn_s_barrier();
    cur ^= 1;
  }
#undef STAGE

  // epilogue: C/D frag layout col=lane&15, row=(lane>>4)*4+j
#pragma unroll
  for (int mi = 0; mi < 4; ++mi)
#pragma unroll
    for (int ni = 0; ni < 4; ++ni)
#pragma unroll
      for (int j = 0; j < 4; ++j) {
        int m = m0 + wm*64 + mi*16 + (lane>>4)*4 + j;
        int n = n0 + wn*64 + ni*16 + (lane&15);
        float v = acc[mi][ni][j];
        if (EPI == 0) {
          C[(size_t)m*ldc + n] = v;
        } else if (EPI == 2) {
          v += bias[n];
          v = (v > 20.f) ? v : log1pf(__expf(v));
          C[(size_t)m*ldc + n] = v;
        }
      }
}

// ---------------- x_proj split-K(4) reduce: -> xpo fp32 + dlow hi/lo ----------
__global__ __launch_bounds__(256) void reduce_xproj(
    const float* __restrict__ P, float* __restrict__ xpo,
    unsigned short* __restrict__ dh, unsigned short* __restrict__ dl) {
  int idx = blockIdx.x * 256 + threadIdx.x;   // NROWS*128
  int m = idx >> 7, n = idx & 127;
  float v = 0.f;
#pragma unroll
  for (int s = 0; s < 4; ++s) v += P[(size_t)s * NROWS * 128 + idx];
  if (n < XPO_W) xpo[(size_t)m * XPO_W + n] = v;
  if (n < 64) {   // cols 48..63 multiply dtw zeros -> harmless
    unsigned short hv = f2bf(v);
    dh[(size_t)m*64 + n] = hv;
    dl[(size_t)m*64 + n] = f2bf(v - bf2f(hv));
  }
}

// ---------------- out_proj split-K(4) reduce + residual -> d_out ----------------
__global__ __launch_bounds__(256) void reduce_out(
    const float* __restrict__ P, const float* __restrict__ x, float* __restrict__ out) {
  int i = blockIdx.x * 256 + threadIdx.x;     // NROWS*DMODEL
  const size_t S = (size_t)NROWS*DMODEL;
  out[i] = x[i] + ((P[i] + P[i + S]) + (P[i + 2*S] + P[i + 3*S]));
}

// ---------------- causal depthwise conv + SiLU: read-once register-rolling ----------------
__global__ __launch_bounds__(256) void conv_silu_kernel(
    const float* __restrict__ xz, const float* __restrict__ w,
    const float* __restrict__ cb,
    unsigned short* __restrict__ uh, unsigned short* __restrict__ ul) {
  int d = blockIdx.x * 256 + threadIdx.x;     // channel
  int l0 = blockIdx.y * CSEG;                 // segment start
  int b = blockIdx.z;
  float xv[CSEG + 3];
#pragma unroll
  for (int i = 0; i < CSEG + 3; ++i) {
    int l = l0 + i - 3;
    xv[i] = (l >= 0) ? xz[((size_t)b*LSEQ + l) * (2*DIN) + d] : 0.f;
  }
  float w0 = w[d*4], w1 = w[d*4+1], w2 = w[d*4+2], w3 = w[d*4+3];
  float cbv = cb[d];
#pragma unroll
  for (int i = 0; i < CSEG; ++i) {
    float acc = cbv;
    acc = fmaf(xv[i],     w0, acc);
    acc = fmaf(xv[i + 1], w1, acc);
    acc = fmaf(xv[i + 2], w2, acc);
    acc = fmaf(xv[i + 3], w3, acc);
    float s = acc / (1.f + __expf(-acc));     // silu
    size_t idx = ((size_t)b*LSEQ + l0 + i) * DIN + d;
    unsigned short hv = f2bf(s);
    uh[idx] = hv;
    ul[idx] = f2bf(s - bf2f(hv));
  }
}

// ---------------- chunked selective scan (NC=32, CL=32, bf16 carries, u hi-only) ----------
__global__ __launch_bounds__(256) void scan_pass1(
    const float* __restrict__ delta,
    const unsigned short* __restrict__ uh,
    const float* __restrict__ xpo, const float* __restrict__ A_log,
    unsigned short* __restrict__ carryA, unsigned short* __restrict__ carryH) {
  int d = blockIdx.x * 256 + threadIdx.x;
  int c = blockIdx.y, b = blockIdx.z;
  float A[16];
  {
    const float4* al = reinterpret_cast<const float4*>(A_log + (size_t)d * NST);
#pragma unroll
    for (int i = 0; i < 4; ++i) {
      float4 t = al[i];
      A[4*i+0] = -__expf(t.x); A[4*i+1] = -__expf(t.y);
      A[4*i+2] = -__expf(t.z); A[4*i+3] = -__expf(t.w);
    }
  }
  float h[16], ap[16];
#pragma unroll
  for (int n = 0; n < 16; ++n) { h[n] = 0.f; ap[n] = 1.f; }
  const float* dp = delta + ((size_t)b*LSEQ + c*CL) * DIN + d;
  const unsigned short* uhp = uh + ((size_t)b*LSEQ + c*CL) * DIN + d;
  const float* bp = xpo   + ((size_t)b*LSEQ + c*CL) * XPO_W + DTR;
  for (int l = 0; l < CL; ++l) {
    float dv = dp[(size_t)l*DIN];
    float uv = bf2f(uhp[(size_t)l*DIN]);
    float du = dv * uv;
    float Bv[16];
    {
      const float4* b4 = reinterpret_cast<const float4*>(bp + (size_t)l*XPO_W);
#pragma unroll
      for (int i = 0; i < 4; ++i) {
        float4 t = b4[i];
        Bv[4*i+0] = t.x; Bv[4*i+1] = t.y; Bv[4*i+2] = t.z; Bv[4*i+3] = t.w;
      }
    }
#pragma unroll
    for (int n = 0; n < 16; ++n) {
      float a = __expf(dv * A[n]);
      ap[n] *= a;
      h[n] = fmaf(a, h[n], du * Bv[n]);
    }
  }
  size_t ci = (((size_t)b*NC + c) * DIN + d) * NST;   // bf16 elements
  uint4* ca = reinterpret_cast<uint4*>(carryA + ci);
  uint4* ch = reinterpret_cast<uint4*>(carryH + ci);
  ca[0] = make_uint4(pk2(ap[0],ap[1]), pk2(ap[2],ap[3]), pk2(ap[4],ap[5]), pk2(ap[6],ap[7]));
  ca[1] = make_uint4(pk2(ap[8],ap[9]), pk2(ap[10],ap[11]), pk2(ap[12],ap[13]), pk2(ap[14],ap[15]));
  ch[0] = make_uint4(pk2(h[0],h[1]), pk2(h[2],h[3]), pk2(h[4],h[5]), pk2(h[6],h[7]));
  ch[1] = make_uint4(pk2(h[8],h[9]), pk2(h[10],h[11]), pk2(h[12],h[13]), pk2(h[14],h[15]));
}

__global__ __launch_bounds__(256) void scan_mid(
    const unsigned short* __restrict__ carryA, unsigned short* __restrict__ carryH) {
  int idx = blockIdx.x * 256 + threadIdx.x;   // [0, BSZ*DIN*NST)
  int b = idx / (DIN*NST);
  int rem = idx - b * DIN*NST;
  float h = 0.f;
#pragma unroll
  for (int c = 0; c < NC; ++c) {
    size_t i = ((size_t)b*NC + c) * (DIN*NST) + rem;
    float a = bf2f(carryA[i]);
    float e = bf2f(carryH[i]);
    carryH[i] = f2bf(h);
    h = fmaf(a, h, e);
  }
}

__global__ __launch_bounds__(256) void scan_pass2(
    const float* __restrict__ delta,
    const unsigned short* __restrict__ uh,
    const float* __restrict__ xpo, const float* __restrict__ xz,
    const float* __restrict__ A_log, const float* __restrict__ Dp,
    const unsigned short* __restrict__ carryH,
    unsigned short* __restrict__ yh, unsigned short* __restrict__ yl) {
  int d = blockIdx.x * 256 + threadIdx.x;
  int c = blockIdx.y, b = blockIdx.z;
  float A[16];
  {
    const float4* al = reinterpret_cast<const float4*>(A_log + (size_t)d * NST);
#pragma unroll
    for (int i = 0; i < 4; ++i) {
      float4 t = al[i];
      A[4*i+0] = -__expf(t.x); A[4*i+1] = -__expf(t.y);
      A[4*i+2] = -__expf(t.z); A[4*i+3] = -__expf(t.w);
    }
  }
  float h[16];
  size_t ci = (((size_t)b*NC + c) * DIN + d) * NST;
  {
    const uint4* ch4 = reinterpret_cast<const uint4*>(carryH + ci);
    uint4 t0 = ch4[0], t1 = ch4[1];
    h[0] = bf2f(t0.x & 0xffff); h[1] = bf2f(t0.x >> 16);
    h[2] = bf2f(t0.y & 0xffff); h[3] = bf2f(t0.y >> 16);
    h[4] = bf2f(t0.z & 0xffff); h[5] = bf2f(t0.z >> 16);
    h[6] = bf2f(t0.w & 0xffff); h[7] = bf2f(t0.w >> 16);
    h[8] = bf2f(t1.x & 0xffff); h[9] = bf2f(t1.x >> 16);
    h[10] = bf2f(t1.y & 0xffff); h[11] = bf2f(t1.y >> 16);
    h[12] = bf2f(t1.z & 0xffff); h[13] = bf2f(t1.z >> 16);
    h[14] = bf2f(t1.w & 0xffff); h[15] = bf2f(t1.w >> 16);
  }
  float Dd = Dp[d];
  const float* dp = delta + ((size_t)b*LSEQ + c*CL) * DIN + d;
  const unsigned short* uhp = uh + ((size_t)b*LSEQ + c*CL) * DIN + d;
  const float* bp = xpo   + ((size_t)b*LSEQ + c*CL) * XPO_W + DTR;
  const float* zp = xz    + ((size_t)b*LSEQ + c*CL) * (2*DIN) + DIN + d;
  size_t yi0 = ((size_t)b*LSEQ + c*CL) * DIN + d;
  for (int l = 0; l < CL; ++l) {
    float dv = dp[(size_t)l*DIN];
    float uv = bf2f(uhp[(size_t)l*DIN]);
    float du = dv * uv;
    float Bv[16], Cv[16];
    {
      const float4* b4 = reinterpret_cast<const float4*>(bp + (size_t)l*XPO_W);
#pragma unroll
      for (int i = 0; i < 4; ++i) {
        float4 t = b4[i];
        Bv[4*i+0] = t.x; Bv[4*i+1] = t.y; Bv[4*i+2] = t.z; Bv[4*i+3] = t.w;
        float4 tc = b4[i+4];
        Cv[4*i+0] = tc.x; Cv[4*i+1] = tc.y; Cv[4*i+2] = tc.z; Cv[4*i+3] = tc.w;
      }
    }
    float p = 0.f;
#pragma unroll
    for (int n = 0; n < 16; ++n) {
      float a = __expf(dv * A[n]);
      h[n] = fmaf(a, h[n], du * Bv[n]);
      p = fmaf(h[n], Cv[n], p);
    }
    float z = zp[(size_t)l*(2*DIN)];
    float sz = z / (1.f + __expf(-z));
    float yv = fmaf(uv, Dd, p) * sz;
    unsigned short hv = f2bf(yv);
    yh[yi0 + (size_t)l*DIN] = hv;
    yl[yi0 + (size_t)l*DIN] = f2bf(yv - bf2f(hv));
  }
}

extern "C" void kernel_launch(void* const* d_in, const int* in_sizes, int n_in,
                              void* d_out, int out_size, void* d_ws, size_t ws_size,
                              hipStream_t stream) {
  const float* x          = (const float*)d_in[0];
  const float* ln_g       = (const float*)d_in[1];
  const float* ln_b       = (const float*)d_in[2];
  const float* in_proj_w  = (const float*)d_in[3];   // (1536,384)
  const float* conv_w     = (const float*)d_in[4];   // (768,1,4)
  const float* conv_b     = (const float*)d_in[5];
  const float* x_proj_w   = (const float*)d_in[6];   // (80,768)
  const float* dt_proj_w  = (const float*)d_in[7];   // (768,48)
  const float* dt_proj_b  = (const float*)d_in[8];
  const float* A_log      = (const float*)d_in[9];   // (768,16)
  const float* D_param    = (const float*)d_in[10];
  const float* out_proj_w = (const float*)d_in[11];  // (384,768)

  char* w = (char*)d_ws;
  // region1 (12.58MB): xn hi/lo -> dlow hi/lo -> bf16 carryA/H (lifetimes disjoint)
  unsigned short* xn_h  = (unsigned short*)w;
  unsigned short* xn_l  = xn_h + (size_t)NROWS*DMODEL;
  unsigned short* dlow_h = (unsigned short*)w;
  unsigned short* dlow_l = dlow_h + (size_t)NROWS*64;
  unsigned short* carryA = (unsigned short*)w;                       // 6.29MB
  unsigned short* carryH = carryA + (size_t)BSZ*NC*DIN*NST;          // 6.29MB
  char* p = w + (size_t)NROWS*DMODEL*4;               // 12.58MB
  float* xz = (float*)p;              p += (size_t)NROWS*2*DIN*4;   // 50.33MB
  unsigned short* u_h = (unsigned short*)p;
  unsigned short* u_l = u_h + (size_t)NROWS*DIN;      p += (size_t)NROWS*DIN*4; // 25.17MB
  float* xpo = (float*)p;             p += (size_t)NROWS*XPO_W*4;   // 2.62MB
  float* delta = (float*)p;           p += (size_t)NROWS*DIN*4;     // 25.17MB
  // weight splits for in_proj/x_proj live in the (not yet written) delta region
  unsigned short* inw_h = (unsigned short*)delta;
  unsigned short* inw_l = inw_h + (size_t)1536*384;
  unsigned short* xw_h  = inw_l + (size_t)1536*384;
  unsigned short* xw_l  = xw_h + (size_t)128*768;
  // y2 region doubles as x_proj split-K partials (4 x 8192 x 128 fp32) pre-scan
  unsigned short* y2_h = (unsigned short*)p;
  unsigned short* y2_l = y2_h + (size_t)NROWS*DIN;
  float* xpart = (float*)p;           p += (size_t)NROWS*DIN*4;     // 25.17MB
  unsigned short* dtw_h = (unsigned short*)p;
  unsigned short* dtw_l = dtw_h + (size_t)768*64;
  unsigned short* ow_h  = dtw_l + (size_t)768*64;
  unsigned short* ow_l  = ow_h + (size_t)384*768;
  // out_proj split-K partials reuse xz (dead after scan_pass2): 4 x 8192 x 384 fp32
  float* opart = xz;

  // 0. fused prep: weight splits + LayerNorm
  prep_kernel<<<NWBLK + NROWS/4, 256, 0, stream>>>(
      in_proj_w, x_proj_w, dt_proj_w, out_proj_w,
      inw_h, inw_l, xw_h, xw_l, dtw_h, dtw_l, ow_h, ow_l,
      x, ln_g, ln_b, xn_h, xn_l);

  // 1. in_proj: xz = xn @ in_proj_w^T   (M=8192, N=1536, K=384, T=12)
  gemm_mfma<0><<<dim3(12, 64, 1), 256, 0, stream>>>(xn_h, xn_l, DMODEL, inw_h, inw_l, DMODEL,
      xz, 2*DIN, 0, nullptr, 12);

  // 2. conv + silu -> u hi/lo (read-once, register-rolling)
  conv_silu_kernel<<<dim3(DIN/256, LSEQ/CSEG, BSZ), 256, 0, stream>>>(
      xz, conv_w, conv_b, u_h, u_l);

  // 3. x_proj: split-K partials (S=4, T=6 each) then reduce -> xpo fp32 + dlow hi/lo
  gemm_mfma<0><<<dim3(1, 64, 4), 256, 0, stream>>>(u_h, u_l, DIN, xw_h, xw_l, DIN,
      xpart, 128, (size_t)NROWS*128, nullptr, 6);
  reduce_xproj<<<(NROWS*128)/256, 256, 0, stream>>>(xpart, xpo, dlow_h, dlow_l);

  // 4. dt_proj + bias + softplus -> delta   (M=8192, N=768, Kpad=64, T=2)
  gemm_mfma<2><<<dim3(6, 64, 1), 256, 0, stream>>>(dlow_h, dlow_l, 64, dtw_h, dtw_l, 64,
      delta, DIN, 0, dt_proj_b, 2);

  // 5. chunked selective scan (NC=32) -> y2 hi/lo (overwrites dead xpart)
  {
    dim3 g1(DIN/256, NC, BSZ);
    scan_pass1<<<g1, 256, 0, stream>>>(delta, u_h, xpo, A_log, carryA, carryH);
    scan_mid<<<(BSZ*DIN*NST)/256, 256, 0, stream>>>(carryA, carryH);
    scan_pass2<<<g1, 256, 0, stream>>>(delta, u_h, xpo, xz, A_log, D_param,
                                       carryH, y2_h, y2_l);
  }

  // 6. out_proj split-K (S=4, T=6) -> partials in dead xz, then reduce + residual
  gemm_mfma<0><<<dim3(3, 64, 4), 256, 0, stream>>>(y2_h, y2_l, DIN, ow_h, ow_l, DIN,
      opart, DMODEL, (size_t)NROWS*DMODEL, nullptr, 6);
  reduce_out<<<(NROWS*DMODEL)/256, 256, 0, stream>>>(opart, x, (float*)d_out);
}

// Round 16
// 225.061 us; speedup vs baseline: 1.0735x; 1.0039x over previous
//
#include <hip/hip_runtime.h>
#include <math.h>

#define DMODEL 384
#define DIN 768
#define NST 16
#define DTR 48
#define BSZ 8
#define LSEQ 1024
#define NROWS (BSZ*LSEQ)      // 8192
#define XPO_W (DTR + 2*NST)   // 80
#define CL 32                 // chunk length for scan
#define NC (LSEQ/CL)          // 32 chunks
#define CSEG 32               // conv segment length

typedef __attribute__((ext_vector_type(8))) short bf16x8;
typedef __attribute__((ext_vector_type(4))) float f32x4;

__device__ __forceinline__ unsigned short f2bf(float x) {
  unsigned int u = __float_as_uint(x);
  unsigned int r = u + 0x7fffu + ((u >> 16) & 1u);
  return (unsigned short)(r >> 16);
}
__device__ __forceinline__ float bf2f(unsigned short h) {
  return __uint_as_float(((unsigned int)h) << 16);
}
__device__ __forceinline__ unsigned int pk2(float a, float b) {
  return (unsigned int)f2bf(a) | ((unsigned int)f2bf(b) << 16);
}

__device__ __forceinline__ void gll16(const void* g, void* l) {
  __builtin_amdgcn_global_load_lds(
      (const __attribute__((address_space(1))) void*)g,
      (__attribute__((address_space(3))) void*)l, 16, 0, 0);
}

// ---------------- fused prep: weight splits + LayerNorm ----------------
__device__ __forceinline__ void split_one(const float* src, int ldsrc, int R, int C,
    unsigned short* dh, unsigned short* dl, int Cpad, int i) {
  int r = i / Cpad, c = i - r * Cpad;
  float v = (r < R && c < C) ? src[(size_t)r*ldsrc + c] : 0.f;
  unsigned short hv = f2bf(v);
  dh[i] = hv;
  dl[i] = f2bf(v - bf2f(hv));
}
#define N_INW (1536*384)
#define N_XW  (128*768)
#define N_DTW (768*64)
#define N_OW  (384*768)
#define NWBLK ((N_INW+N_XW+N_DTW+N_OW)/256)   // 4032
__global__ __launch_bounds__(256) void prep_kernel(
    const float* __restrict__ inw, const float* __restrict__ xw,
    const float* __restrict__ dtw, const float* __restrict__ ow,
    unsigned short* inw_h, unsigned short* inw_l,
    unsigned short* xw_h, unsigned short* xw_l,
    unsigned short* dtw_h, unsigned short* dtw_l,
    unsigned short* ow_h, unsigned short* ow_l,
    const float* __restrict__ x, const float* __restrict__ g,
    const float* __restrict__ b,
    unsigned short* __restrict__ xh, unsigned short* __restrict__ xl) {
  if (blockIdx.x < NWBLK) {
    int i = blockIdx.x * 256 + threadIdx.x;
    if (i < N_INW) { split_one(inw, 384, 1536, 384, inw_h, inw_l, 384, i); return; }
    i -= N_INW;
    if (i < N_XW)  { split_one(xw, 768, 80, 768, xw_h, xw_l, 768, i); return; }
    i -= N_XW;
    if (i < N_DTW) { split_one(dtw, 48, 768, 48, dtw_h, dtw_l, 64, i); return; }
    i -= N_DTW;
    split_one(ow, 768, 384, 768, ow_h, ow_l, 768, i);
    return;
  }
  // LayerNorm path: 4 rows per block
  int row = (blockIdx.x - NWBLK) * 4 + (threadIdx.x >> 6);
  int lane = threadIdx.x & 63;
  const float* xr = x + (size_t)row * DMODEL;
  float v[6];
  float s = 0.f, ss = 0.f;
#pragma unroll
  for (int i = 0; i < 6; ++i) { v[i] = xr[lane + i*64]; s += v[i]; ss += v[i]*v[i]; }
#pragma unroll
  for (int off = 32; off; off >>= 1) { s += __shfl_xor(s, off); ss += __shfl_xor(ss, off); }
  float mu = s * (1.f / DMODEL);
  float var = ss * (1.f / DMODEL) - mu * mu;
  float inv = rsqrtf(var + 1e-5f);
#pragma unroll
  for (int i = 0; i < 6; ++i) {
    int c = lane + i*64;
    float o = (v[i] - mu) * inv * g[c] + b[c];
    unsigned short hv = f2bf(o);
    xh[(size_t)row*DMODEL + c] = hv;
    xl[(size_t)row*DMODEL + c] = f2bf(o - bf2f(hv));
  }
}

// ---------------- MFMA split-bf16 GEMM, 2-phase double-buffered (R3-proven) -------------
// C[M,N] (z-slice) = (Ah+Al)[M,K] * (Bh+Bl)[N,K]^T, 3 MFMA terms.
// 128x128 tile, BK=32, 256 threads = 4 waves (2x2), wave tile 64x64.
// EPI: 0 plain, 2 bias+softplus
template<int EPI>
__global__ __launch_bounds__(256, 2) void gemm_mfma(
    const unsigned short* __restrict__ Ah, const unsigned short* __restrict__ Al, int lda,
    const unsigned short* __restrict__ Bh, const unsigned short* __restrict__ Bl, int ldb,
    float* __restrict__ C, int ldc, size_t strideS,
    const float* __restrict__ bias,
    int T) {
  // [buf][arr: Ah,Al,Bh,Bl][cell(512) x 8 bf16] = 64 KB
  __shared__ unsigned short lds[2][4][4096];
  int tid = threadIdx.x;
  int lane = tid & 63, wid = tid >> 6;
  int wm = wid >> 1, wn = wid & 1;

  // bijective XCD swizzle over (x,y); all grids have nwg % 8 == 0
  unsigned nwg = gridDim.x * gridDim.y;
  unsigned bid = blockIdx.y * gridDim.x + blockIdx.x;
  unsigned cpx = nwg >> 3;
  unsigned sw = (bid & 7) * cpx + (bid >> 3);
  unsigned bx = sw % gridDim.x, by = sw / gridDim.x;
  int m0 = by * 128, n0 = bx * 128;
  C += (size_t)blockIdx.z * strideS;
  size_t kofs = (size_t)blockIdx.z * T * 32;

  f32x4 acc[4][4];
#pragma unroll
  for (int i = 0; i < 4; ++i)
#pragma unroll
    for (int j = 0; j < 4; ++j) acc[i][j] = (f32x4){0.f, 0.f, 0.f, 0.f};

  int kgl = lane >> 4, rl = lane & 15;

  // per-wave staging geometry: wave fills cells [wid*128, wid*128+128) per array
  int c0 = wid*128 + lane;        // j=0 cell
  int c1 = wid*128 + 64 + lane;   // j=1 cell
  int r0 = c0 & 127, kg0 = c0 >> 7;
  int r1 = c1 & 127, kg1 = c1 >> 7;

#define STAGE(bf, kt) do { \
    size_t ga0 = (size_t)(m0 + r0) * lda + (kt) + kg0*8 + kofs; \
    size_t gb0 = (size_t)(n0 + r0) * ldb + (kt) + kg0*8 + kofs; \
    size_t ga1 = (size_t)(m0 + r1) * lda + (kt) + kg1*8 + kofs; \
    size_t gb1 = (size_t)(n0 + r1) * ldb + (kt) + kg1*8 + kofs; \
    gll16(Ah + ga0, &lds[bf][0][(wid*128)*8]); \
    gll16(Al + ga0, &lds[bf][1][(wid*128)*8]); \
    gll16(Bh + gb0, &lds[bf][2][(wid*128)*8]); \
    gll16(Bl + gb0, &lds[bf][3][(wid*128)*8]); \
    gll16(Ah + ga1, &lds[bf][0][(wid*128+64)*8]); \
    gll16(Al + ga1, &lds[bf][1][(wid*128+64)*8]); \
    gll16(Bh + gb1, &lds[bf][2][(wid*128+64)*8]); \
    gll16(Bl + gb1, &lds[bf][3][(wid*128+64)*8]); \
  } while (0)

  STAGE(0, 0);
  asm volatile("s_waitcnt vmcnt(0)" ::: "memory");
  __builtin_amdgcn_s_barrier();

  int cur = 0;
  for (int t = 0; t < T; ++t) {
    if (t + 1 < T) {
      STAGE(cur ^ 1, (t + 1) << 5);
    }
    asm volatile("" ::: "memory");
    bf16x8 ah[4], al[4], bh[4], bl[4];
#pragma unroll
    for (int mi = 0; mi < 4; ++mi) {
      int cell = kgl*128 + wm*64 + mi*16 + rl;
      ah[mi] = *reinterpret_cast<const bf16x8*>(&lds[cur][0][cell*8]);
      al[mi] = *reinterpret_cast<const bf16x8*>(&lds[cur][1][cell*8]);
    }
#pragma unroll
    for (int ni = 0; ni < 4; ++ni) {
      int cell = kgl*128 + wn*64 + ni*16 + rl;
      bh[ni] = *reinterpret_cast<const bf16x8*>(&lds[cur][2][cell*8]);
      bl[ni] = *reinterpret_cast<const bf16x8*>(&lds[cur][3][cell*8]);
    }
#pragma unroll
    for (int mi = 0; mi < 4; ++mi)
#pragma unroll
      for (int ni = 0; ni < 4; ++ni) {
        acc[mi][ni] = __builtin_amdgcn_mfma_f32_16x16x32_bf16(ah[mi], bh[ni], acc[mi][ni], 0, 0, 0);
        acc[mi][ni] = __builtin_amdgcn_mfma_f32_16x16x32_bf16(al[mi], bh[ni], acc[mi][ni], 0, 0, 0);
        acc[mi][ni] = __builtin_amdgcn_mfma_f32_16x16x32_bf16(ah[mi], bl[ni], acc[mi][ni], 0, 0, 0);
      }
    asm volatile("s_waitcnt vmcnt(0)" ::: "memory");
    __builtin_amdgcn_s_barrier();
    cur ^= 1;
  }
#undef STAGE

  // epilogue: C/D frag layout col=lane&15, row=(lane>>4)*4+j
#pragma unroll
  for (int mi = 0; mi < 4; ++mi)
#pragma unroll
    for (int ni = 0; ni < 4; ++ni)
#pragma unroll
      for (int j = 0; j < 4; ++j) {
        int m = m0 + wm*64 + mi*16 + (lane>>4)*4 + j;
        int n = n0 + wn*64 + ni*16 + (lane&15);
        float v = acc[mi][ni][j];
        if (EPI == 0) {
          C[(size_t)m*ldc + n] = v;
        } else if (EPI == 2) {
          v += bias[n];
          v = (v > 20.f) ? v : log1pf(__expf(v));
          C[(size_t)m*ldc + n] = v;
        }
      }
}

// ------- out_proj: 64x64-tile M-split GEMM, residual fused, no partials -------
// C[M,384] = (Ah+Al)[M,768] * (Bh+Bl)[384,768]^T + res. BK=32, 256 thr = 4 waves (2x2),
// wave tile 32x32, acc[2][2], 12 MFMA/kstep, 32 KB LDS, same 2-phase skeleton.
__global__ __launch_bounds__(256, 2) void gemm64_res(
    const unsigned short* __restrict__ Ah, const unsigned short* __restrict__ Al, int lda,
    const unsigned short* __restrict__ Bh, const unsigned short* __restrict__ Bl, int ldb,
    float* __restrict__ C, int ldc,
    const float* __restrict__ res, int T) {
  __shared__ unsigned short lds[2][4][2048];   // [buf][Ah,Al,Bh,Bl][256 cells x 8]
  int tid = threadIdx.x;
  int lane = tid & 63, wid = tid >> 6;
  int wm = wid >> 1, wn = wid & 1;

  unsigned nwg = gridDim.x * gridDim.y;
  unsigned bid = blockIdx.y * gridDim.x + blockIdx.x;
  unsigned cpx = nwg >> 3;
  unsigned sw = (bid & 7) * cpx + (bid >> 3);
  unsigned bx = sw % gridDim.x, by = sw / gridDim.x;
  int m0 = by * 64, n0 = bx * 64;

  f32x4 acc[2][2];
#pragma unroll
  for (int i = 0; i < 2; ++i)
#pragma unroll
    for (int j = 0; j < 2; ++j) acc[i][j] = (f32x4){0.f, 0.f, 0.f, 0.f};

  int kgl = lane >> 4, rl = lane & 15;

  // staging: per array 256 cells (kg*64 + row); cell = tid; row = tid&63, kg = tid>>6
  int srow = tid & 63, skg = tid >> 6;
  size_t ga = (size_t)(m0 + srow) * lda + skg * 8;
  size_t gb = (size_t)(n0 + srow) * ldb + skg * 8;
  int dst = tid * 8;   // = (wid*64)*8 wave-uniform base + lane*16B

#define STAGE64(bf, kt) do { \
    gll16(Ah + ga + (kt), &lds[bf][0][dst]); \
    gll16(Al + ga + (kt), &lds[bf][1][dst]); \
    gll16(Bh + gb + (kt), &lds[bf][2][dst]); \
    gll16(Bl + gb + (kt), &lds[bf][3][dst]); \
  } while (0)

  STAGE64(0, 0);
  asm volatile("s_waitcnt vmcnt(0)" ::: "memory");
  __builtin_amdgcn_s_barrier();

  int cur = 0;
  for (int t = 0; t < T; ++t) {
    if (t + 1 < T) {
      STAGE64(cur ^ 1, (t + 1) << 5);
    }
    asm volatile("" ::: "memory");
    bf16x8 ah[2], al[2], bh[2], bl[2];
#pragma unroll
    for (int mi = 0; mi < 2; ++mi) {
      int cell = kgl*64 + wm*32 + mi*16 + rl;
      ah[mi] = *reinterpret_cast<const bf16x8*>(&lds[cur][0][cell*8]);
      al[mi] = *reinterpret_cast<const bf16x8*>(&lds[cur][1][cell*8]);
    }
#pragma unroll
    for (int ni = 0; ni < 2; ++ni) {
      int cell = kgl*64 + wn*32 + ni*16 + rl;
      bh[ni] = *reinterpret_cast<const bf16x8*>(&lds[cur][2][cell*8]);
      bl[ni] = *reinterpret_cast<const bf16x8*>(&lds[cur][3][cell*8]);
    }
#pragma unroll
    for (int mi = 0; mi < 2; ++mi)
#pragma unroll
      for (int ni = 0; ni < 2; ++ni) {
        acc[mi][ni] = __builtin_amdgcn_mfma_f32_16x16x32_bf16(ah[mi], bh[ni], acc[mi][ni], 0, 0, 0);
        acc[mi][ni] = __builtin_amdgcn_mfma_f32_16x16x32_bf16(al[mi], bh[ni], acc[mi][ni], 0, 0, 0);
        acc[mi][ni] = __builtin_amdgcn_mfma_f32_16x16x32_bf16(ah[mi], bl[ni], acc[mi][ni], 0, 0, 0);
      }
    asm volatile("s_waitcnt vmcnt(0)" ::: "memory");
    __builtin_amdgcn_s_barrier();
    cur ^= 1;
  }
#undef STAGE64

#pragma unroll
  for (int mi = 0; mi < 2; ++mi)
#pragma unroll
    for (int ni = 0; ni < 2; ++ni)
#pragma unroll
      for (int j = 0; j < 4; ++j) {
        int m = m0 + wm*32 + mi*16 + (lane>>4)*4 + j;
        int n = n0 + wn*32 + ni*16 + rl;
        C[(size_t)m*ldc + n] = acc[mi][ni][j] + res[(size_t)m*ldc + n];
      }
}

// ---------------- x_proj split-K(4) reduce: -> xpo fp32 + dlow hi/lo ----------
__global__ __launch_bounds__(256) void reduce_xproj(
    const float* __restrict__ P, float* __restrict__ xpo,
    unsigned short* __restrict__ dh, unsigned short* __restrict__ dl) {
  int idx = blockIdx.x * 256 + threadIdx.x;   // NROWS*128
  int m = idx >> 7, n = idx & 127;
  float v = 0.f;
#pragma unroll
  for (int s = 0; s < 4; ++s) v += P[(size_t)s * NROWS * 128 + idx];
  if (n < XPO_W) xpo[(size_t)m * XPO_W + n] = v;
  if (n < 64) {   // cols 48..63 multiply dtw zeros -> harmless
    unsigned short hv = f2bf(v);
    dh[(size_t)m*64 + n] = hv;
    dl[(size_t)m*64 + n] = f2bf(v - bf2f(hv));
  }
}

// ---------------- causal depthwise conv + SiLU: read-once register-rolling ----------------
__global__ __launch_bounds__(256) void conv_silu_kernel(
    const float* __restrict__ xz, const float* __restrict__ w,
    const float* __restrict__ cb,
    unsigned short* __restrict__ uh, unsigned short* __restrict__ ul) {
  int d = blockIdx.x * 256 + threadIdx.x;     // channel
  int l0 = blockIdx.y * CSEG;                 // segment start
  int b = blockIdx.z;
  float xv[CSEG + 3];
#pragma unroll
  for (int i = 0; i < CSEG + 3; ++i) {
    int l = l0 + i - 3;
    xv[i] = (l >= 0) ? xz[((size_t)b*LSEQ + l) * (2*DIN) + d] : 0.f;
  }
  float w0 = w[d*4], w1 = w[d*4+1], w2 = w[d*4+2], w3 = w[d*4+3];
  float cbv = cb[d];
#pragma unroll
  for (int i = 0; i < CSEG; ++i) {
    float acc = cbv;
    acc = fmaf(xv[i],     w0, acc);
    acc = fmaf(xv[i + 1], w1, acc);
    acc = fmaf(xv[i + 2], w2, acc);
    acc = fmaf(xv[i + 3], w3, acc);
    float s = acc / (1.f + __expf(-acc));     // silu
    size_t idx = ((size_t)b*LSEQ + l0 + i) * DIN + d;
    unsigned short hv = f2bf(s);
    uh[idx] = hv;
    ul[idx] = f2bf(s - bf2f(hv));
  }
}

// ---------------- chunked selective scan (NC=32, CL=32, bf16 carries, u hi-only) ----------
__global__ __launch_bounds__(256) void scan_pass1(
    const float* __restrict__ delta,
    const unsigned short* __restrict__ uh,
    const float* __restrict__ xpo, const float* __restrict__ A_log,
    unsigned short* __restrict__ carryA, unsigned short* __restrict__ carryH) {
  int d = blockIdx.x * 256 + threadIdx.x;
  int c = blockIdx.y, b = blockIdx.z;
  float A[16];
  {
    const float4* al = reinterpret_cast<const float4*>(A_log + (size_t)d * NST);
#pragma unroll
    for (int i = 0; i < 4; ++i) {
      float4 t = al[i];
      A[4*i+0] = -__expf(t.x); A[4*i+1] = -__expf(t.y);
      A[4*i+2] = -__expf(t.z); A[4*i+3] = -__expf(t.w);
    }
  }
  float h[16], ap[16];
#pragma unroll
  for (int n = 0; n < 16; ++n) { h[n] = 0.f; ap[n] = 1.f; }
  const float* dp = delta + ((size_t)b*LSEQ + c*CL) * DIN + d;
  const unsigned short* uhp = uh + ((size_t)b*LSEQ + c*CL) * DIN + d;
  const float* bp = xpo   + ((size_t)b*LSEQ + c*CL) * XPO_W + DTR;
  for (int l = 0; l < CL; ++l) {
    float dv = dp[(size_t)l*DIN];
    float uv = bf2f(uhp[(size_t)l*DIN]);
    float du = dv * uv;
    float Bv[16];
    {
      const float4* b4 = reinterpret_cast<const float4*>(bp + (size_t)l*XPO_W);
#pragma unroll
      for (int i = 0; i < 4; ++i) {
        float4 t = b4[i];
        Bv[4*i+0] = t.x; Bv[4*i+1] = t.y; Bv[4*i+2] = t.z; Bv[4*i+3] = t.w;
      }
    }
#pragma unroll
    for (int n = 0; n < 16; ++n) {
      float a = __expf(dv * A[n]);
      ap[n] *= a;
      h[n] = fmaf(a, h[n], du * Bv[n]);
    }
  }
  size_t ci = (((size_t)b*NC + c) * DIN + d) * NST;   // bf16 elements
  uint4* ca = reinterpret_cast<uint4*>(carryA + ci);
  uint4* ch = reinterpret_cast<uint4*>(carryH + ci);
  ca[0] = make_uint4(pk2(ap[0],ap[1]), pk2(ap[2],ap[3]), pk2(ap[4],ap[5]), pk2(ap[6],ap[7]));
  ca[1] = make_uint4(pk2(ap[8],ap[9]), pk2(ap[10],ap[11]), pk2(ap[12],ap[13]), pk2(ap[14],ap[15]));
  ch[0] = make_uint4(pk2(h[0],h[1]), pk2(h[2],h[3]), pk2(h[4],h[5]), pk2(h[6],h[7]));
  ch[1] = make_uint4(pk2(h[8],h[9]), pk2(h[10],h[11]), pk2(h[12],h[13]), pk2(h[14],h[15]));
}

__global__ __launch_bounds__(256) void scan_mid(
    const unsigned short* __restrict__ carryA, unsigned short* __restrict__ carryH) {
  int idx = blockIdx.x * 256 + threadIdx.x;   // [0, BSZ*DIN*NST)
  int b = idx / (DIN*NST);
  int rem = idx - b * DIN*NST;
  float h = 0.f;
#pragma unroll
  for (int c = 0; c < NC; ++c) {
    size_t i = ((size_t)b*NC + c) * (DIN*NST) + rem;
    float a = bf2f(carryA[i]);
    float e = bf2f(carryH[i]);
    carryH[i] = f2bf(h);
    h = fmaf(a, h, e);
  }
}

__global__ __launch_bounds__(256) void scan_pass2(
    const float* __restrict__ delta,
    const unsigned short* __restrict__ uh,
    const float* __restrict__ xpo, const float* __restrict__ xz,
    const float* __restrict__ A_log, const float* __restrict__ Dp,
    const unsigned short* __restrict__ carryH,
    unsigned short* __restrict__ yh, unsigned short* __restrict__ yl) {
  int d = blockIdx.x * 256 + threadIdx.x;
  int c = blockIdx.y, b = blockIdx.z;
  float A[16];
  {
    const float4* al = reinterpret_cast<const float4*>(A_log + (size_t)d * NST);
#pragma unroll
    for (int i = 0; i < 4; ++i) {
      float4 t = al[i];
      A[4*i+0] = -__expf(t.x); A[4*i+1] = -__expf(t.y);
      A[4*i+2] = -__expf(t.z); A[4*i+3] = -__expf(t.w);
    }
  }
  float h[16];
  size_t ci = (((size_t)b*NC + c) * DIN + d) * NST;
  {
    const uint4* ch4 = reinterpret_cast<const uint4*>(carryH + ci);
    uint4 t0 = ch4[0], t1 = ch4[1];
    h[0] = bf2f(t0.x & 0xffff); h[1] = bf2f(t0.x >> 16);
    h[2] = bf2f(t0.y & 0xffff); h[3] = bf2f(t0.y >> 16);
    h[4] = bf2f(t0.z & 0xffff); h[5] = bf2f(t0.z >> 16);
    h[6] = bf2f(t0.w & 0xffff); h[7] = bf2f(t0.w >> 16);
    h[8] = bf2f(t1.x & 0xffff); h[9] = bf2f(t1.x >> 16);
    h[10] = bf2f(t1.y & 0xffff); h[11] = bf2f(t1.y >> 16);
    h[12] = bf2f(t1.z & 0xffff); h[13] = bf2f(t1.z >> 16);
    h[14] = bf2f(t1.w & 0xffff); h[15] = bf2f(t1.w >> 16);
  }
  float Dd = Dp[d];
  const float* dp = delta + ((size_t)b*LSEQ + c*CL) * DIN + d;
  const unsigned short* uhp = uh + ((size_t)b*LSEQ + c*CL) * DIN + d;
  const float* bp = xpo   + ((size_t)b*LSEQ + c*CL) * XPO_W + DTR;
  const float* zp = xz    + ((size_t)b*LSEQ + c*CL) * (2*DIN) + DIN + d;
  size_t yi0 = ((size_t)b*LSEQ + c*CL) * DIN + d;
  for (int l = 0; l < CL; ++l) {
    float dv = dp[(size_t)l*DIN];
    float uv = bf2f(uhp[(size_t)l*DIN]);
    float du = dv * uv;
    float Bv[16], Cv[16];
    {
      const float4* b4 = reinterpret_cast<const float4*>(bp + (size_t)l*XPO_W);
#pragma unroll
      for (int i = 0; i < 4; ++i) {
        float4 t = b4[i];
        Bv[4*i+0] = t.x; Bv[4*i+1] = t.y; Bv[4*i+2] = t.z; Bv[4*i+3] = t.w;
        float4 tc = b4[i+4];
        Cv[4*i+0] = tc.x; Cv[4*i+1] = tc.y; Cv[4*i+2] = tc.z; Cv[4*i+3] = tc.w;
      }
    }
    float p = 0.f;
#pragma unroll
    for (int n = 0; n < 16; ++n) {
      float a = __expf(dv * A[n]);
      h[n] = fmaf(a, h[n], du * Bv[n]);
      p = fmaf(h[n], Cv[n], p);
    }
    float z = zp[(size_t)l*(2*DIN)];
    float sz = z / (1.f + __expf(-z));
    float yv = fmaf(uv, Dd, p) * sz;
    unsigned short hv = f2bf(yv);
    yh[yi0 + (size_t)l*DIN] = hv;
    yl[yi0 + (size_t)l*DIN] = f2bf(yv - bf2f(hv));
  }
}

extern "C" void kernel_launch(void* const* d_in, const int* in_sizes, int n_in,
                              void* d_out, int out_size, void* d_ws, size_t ws_size,
                              hipStream_t stream) {
  const float* x          = (const float*)d_in[0];
  const float* ln_g       = (const float*)d_in[1];
  const float* ln_b       = (const float*)d_in[2];
  const float* in_proj_w  = (const float*)d_in[3];   // (1536,384)
  const float* conv_w     = (const float*)d_in[4];   // (768,1,4)
  const float* conv_b     = (const float*)d_in[5];
  const float* x_proj_w   = (const float*)d_in[6];   // (80,768)
  const float* dt_proj_w  = (const float*)d_in[7];   // (768,48)
  const float* dt_proj_b  = (const float*)d_in[8];
  const float* A_log      = (const float*)d_in[9];   // (768,16)
  const float* D_param    = (const float*)d_in[10];
  const float* out_proj_w = (const float*)d_in[11];  // (384,768)

  char* w = (char*)d_ws;
  // region1 (12.58MB): xn hi/lo -> dlow hi/lo -> bf16 carryA/H (lifetimes disjoint)
  unsigned short* xn_h  = (unsigned short*)w;
  unsigned short* xn_l  = xn_h + (size_t)NROWS*DMODEL;
  unsigned short* dlow_h = (unsigned short*)w;
  unsigned short* dlow_l = dlow_h + (size_t)NROWS*64;
  unsigned short* carryA = (unsigned short*)w;                       // 6.29MB
  unsigned short* carryH = carryA + (size_t)BSZ*NC*DIN*NST;          // 6.29MB
  char* p = w + (size_t)NROWS*DMODEL*4;               // 12.58MB
  float* xz = (float*)p;              p += (size_t)NROWS*2*DIN*4;   // 50.33MB
  unsigned short* u_h = (unsigned short*)p;
  unsigned short* u_l = u_h + (size_t)NROWS*DIN;      p += (size_t)NROWS*DIN*4; // 25.17MB
  float* xpo = (float*)p;             p += (size_t)NROWS*XPO_W*4;   // 2.62MB
  float* delta = (float*)p;           p += (size_t)NROWS*DIN*4;     // 25.17MB
  // weight splits for in_proj/x_proj live in the (not yet written) delta region
  unsigned short* inw_h = (unsigned short*)delta;
  unsigned short* inw_l = inw_h + (size_t)1536*384;
  unsigned short* xw_h  = inw_l + (size_t)1536*384;
  unsigned short* xw_l  = xw_h + (size_t)128*768;
  // y2 region doubles as x_proj split-K partials (4 x 8192 x 128 fp32) pre-scan
  unsigned short* y2_h = (unsigned short*)p;
  unsigned short* y2_l = y2_h + (size_t)NROWS*DIN;
  float* xpart = (float*)p;           p += (size_t)NROWS*DIN*4;     // 25.17MB
  unsigned short* dtw_h = (unsigned short*)p;
  unsigned short* dtw_l = dtw_h + (size_t)768*64;
  unsigned short* ow_h  = dtw_l + (size_t)768*64;
  unsigned short* ow_l  = ow_h + (size_t)384*768;

  // 0. fused prep: weight splits + LayerNorm
  prep_kernel<<<NWBLK + NROWS/4, 256, 0, stream>>>(
      in_proj_w, x_proj_w, dt_proj_w, out_proj_w,
      inw_h, inw_l, xw_h, xw_l, dtw_h, dtw_l, ow_h, ow_l,
      x, ln_g, ln_b, xn_h, xn_l);

  // 1. in_proj: xz = xn @ in_proj_w^T   (M=8192, N=1536, K=384, T=12)
  gemm_mfma<0><<<dim3(12, 64, 1), 256, 0, stream>>>(xn_h, xn_l, DMODEL, inw_h, inw_l, DMODEL,
      xz, 2*DIN, 0, nullptr, 12);

  // 2. conv + silu -> u hi/lo (read-once, register-rolling)
  conv_silu_kernel<<<dim3(DIN/256, LSEQ/CSEG, BSZ), 256, 0, stream>>>(
      xz, conv_w, conv_b, u_h, u_l);

  // 3. x_proj: split-K partials (S=4, T=6 each) then reduce -> xpo fp32 + dlow hi/lo
  gemm_mfma<0><<<dim3(1, 64, 4), 256, 0, stream>>>(u_h, u_l, DIN, xw_h, xw_l, DIN,
      xpart, 128, (size_t)NROWS*128, nullptr, 6);
  reduce_xproj<<<(NROWS*128)/256, 256, 0, stream>>>(xpart, xpo, dlow_h, dlow_l);

  // 4. dt_proj + bias + softplus -> delta   (M=8192, N=768, Kpad=64, T=2)
  gemm_mfma<2><<<dim3(6, 64, 1), 256, 0, stream>>>(dlow_h, dlow_l, 64, dtw_h, dtw_l, 64,
      delta, DIN, 0, dt_proj_b, 2);

  // 5. chunked selective scan (NC=32) -> y2 hi/lo (overwrites dead xpart)
  {
    dim3 g1(DIN/256, NC, BSZ);
    scan_pass1<<<g1, 256, 0, stream>>>(delta, u_h, xpo, A_log, carryA, carryH);
    scan_mid<<<(BSZ*DIN*NST)/256, 256, 0, stream>>>(carryA, carryH);
    scan_pass2<<<g1, 256, 0, stream>>>(delta, u_h, xpo, xz, A_log, D_param,
                                       carryH, y2_h, y2_l);
  }

  // 6. out_proj: 64x64 M-split, residual fused, direct to d_out (T=24)
  gemm64_res<<<dim3(DMODEL/64, NROWS/64), 256, 0, stream>>>(y2_h, y2_l, DIN,
      ow_h, ow_l, DIN, (float*)d_out, DMODEL, x, 24);
}